// Round 2
// baseline (237.229 us; speedup 1.0000x reference)
//
#include <hip/hip_runtime.h>
#include <math.h>

#define NEGC (-1000.0f)

// ---------- zero the adj matrix region (2176*2176 floats = 1183744 float4) ----------
__global__ __launch_bounds__(256) void kzero_adj(float4* __restrict__ out4) {
    const int i = blockIdx.x * 256 + threadIdx.x;
    if (i < 1183744) out4[i] = make_float4(0.f, 0.f, 0.f, 0.f);
}

// ---------- K1: A2 = seg @ W1[:, :512]^T + b1   (128x256)
//             B2 = vid @ W1[:, 512:]^T          (2048x256) ----------
__global__ __launch_bounds__(256) void k1_gemm(
    const float* __restrict__ seg, const float* __restrict__ vid,
    const float* __restrict__ W1, const float* __restrict__ b1,
    float* __restrict__ A2, float* __restrict__ B2)
{
    __shared__ float Xs[32][64];   // [kk][row]
    __shared__ float Ws[32][64];   // [kk][col]
    const int tid = threadIdx.x;
    const int tx = tid & 15, ty = tid >> 4;
    const int lr = tid >> 2;
    const int lk = (tid & 3) * 8;
    const int colBase = blockIdx.x * 64;
    const int rowBase = blockIdx.y * 64;
    const bool isSeg = (rowBase < 128);
    const float* __restrict__ X = isSeg ? seg : vid;
    const int xRow = isSeg ? rowBase : (rowBase - 128);
    const int wOff = isSeg ? 0 : 512;

    float acc[4][4] = {};

    for (int k0 = 0; k0 < 512; k0 += 32) {
        const float* xp = X + (size_t)(xRow + lr) * 512 + (k0 + lk);
        const float4 xa = *(const float4*)xp;
        const float4 xb = *(const float4*)(xp + 4);
        const float* wp = W1 + (size_t)(colBase + lr) * 1024 + (wOff + k0 + lk);
        const float4 wa = *(const float4*)wp;
        const float4 wb = *(const float4*)(wp + 4);
        __syncthreads();
        Xs[lk + 0][lr] = xa.x; Xs[lk + 1][lr] = xa.y;
        Xs[lk + 2][lr] = xa.z; Xs[lk + 3][lr] = xa.w;
        Xs[lk + 4][lr] = xb.x; Xs[lk + 5][lr] = xb.y;
        Xs[lk + 6][lr] = xb.z; Xs[lk + 7][lr] = xb.w;
        Ws[lk + 0][lr] = wa.x; Ws[lk + 1][lr] = wa.y;
        Ws[lk + 2][lr] = wa.z; Ws[lk + 3][lr] = wa.w;
        Ws[lk + 4][lr] = wb.x; Ws[lk + 5][lr] = wb.y;
        Ws[lk + 6][lr] = wb.z; Ws[lk + 7][lr] = wb.w;
        __syncthreads();
        #pragma unroll
        for (int kk = 0; kk < 32; ++kk) {
            const float4 a4 = *(const float4*)&Xs[kk][4 * ty];
            const float4 b4 = *(const float4*)&Ws[kk][4 * tx];
            const float* a = (const float*)&a4;
            const float* b = (const float*)&b4;
            #pragma unroll
            for (int i = 0; i < 4; ++i)
                #pragma unroll
                for (int j = 0; j < 4; ++j)
                    acc[i][j] = fmaf(a[i], b[j], acc[i][j]);
        }
    }

    float* __restrict__ outp = (isSeg ? A2 : B2) + (size_t)xRow * 256;
    const int c = colBase + 4 * tx;
    #pragma unroll
    for (int i = 0; i < 4; ++i) {
        float4 v = make_float4(acc[i][0], acc[i][1], acc[i][2], acc[i][3]);
        if (isSeg) {
            v.x += b1[c + 0]; v.y += b1[c + 1]; v.z += b1[c + 2]; v.w += b1[c + 3];
        }
        *(float4*)(outp + (size_t)(4 * ty + i) * 256 + c) = v;
    }
}

// ---------- K2: logitsT[s][n] = sum_h relu(A2[n][h]+B2[s][h])*W2[h] + b2
//             lsT = log_sigmoid(logitsT) ----------
__global__ __launch_bounds__(256) void k2_logits(
    const float* __restrict__ A2, const float* __restrict__ B2,
    const float* __restrict__ W2, const float* __restrict__ b2p,
    float* __restrict__ logitsT, float* __restrict__ lsT)
{
    __shared__ float As[32][64];   // [kk][n]
    __shared__ float Bs[32][64];   // [kk][s]
    __shared__ float w2s[256];
    const int tid = threadIdx.x;
    const int tx = tid & 15, ty = tid >> 4;
    const int lr = tid >> 2;
    const int lk = (tid & 3) * 8;
    const int nBase = blockIdx.x * 64;
    const int sBase = blockIdx.y * 64;
    w2s[tid] = W2[tid];
    const float b2v = b2p[0];

    float acc[4][4] = {};   // [i:n][j:s]

    for (int k0 = 0; k0 < 256; k0 += 32) {
        const float* ap = A2 + (size_t)(nBase + lr) * 256 + (k0 + lk);
        const float4 aa = *(const float4*)ap;
        const float4 ab = *(const float4*)(ap + 4);
        const float* bp = B2 + (size_t)(sBase + lr) * 256 + (k0 + lk);
        const float4 ba = *(const float4*)bp;
        const float4 bb = *(const float4*)(bp + 4);
        __syncthreads();
        As[lk + 0][lr] = aa.x; As[lk + 1][lr] = aa.y;
        As[lk + 2][lr] = aa.z; As[lk + 3][lr] = aa.w;
        As[lk + 4][lr] = ab.x; As[lk + 5][lr] = ab.y;
        As[lk + 6][lr] = ab.z; As[lk + 7][lr] = ab.w;
        Bs[lk + 0][lr] = ba.x; Bs[lk + 1][lr] = ba.y;
        Bs[lk + 2][lr] = ba.z; Bs[lk + 3][lr] = ba.w;
        Bs[lk + 4][lr] = bb.x; Bs[lk + 5][lr] = bb.y;
        Bs[lk + 6][lr] = bb.z; Bs[lk + 7][lr] = bb.w;
        __syncthreads();
        #pragma unroll
        for (int kk = 0; kk < 32; ++kk) {
            const float w = w2s[k0 + kk];
            const float4 a4 = *(const float4*)&As[kk][4 * ty];
            const float4 b4 = *(const float4*)&Bs[kk][4 * tx];
            const float* a = (const float*)&a4;
            const float* b = (const float*)&b4;
            #pragma unroll
            for (int i = 0; i < 4; ++i)
                #pragma unroll
                for (int j = 0; j < 4; ++j)
                    acc[i][j] = fmaf(fmaxf(a[i] + b[j], 0.0f), w, acc[i][j]);
        }
    }

    const int nb = nBase + 4 * ty;
    #pragma unroll
    for (int j = 0; j < 4; ++j) {
        const int s = sBase + 4 * tx + j;
        float4 lg, ls;
        float* lgp = (float*)&lg;
        float* lsp = (float*)&ls;
        #pragma unroll
        for (int i = 0; i < 4; ++i) {
            const float x = acc[i][j] + b2v;
            lgp[i] = x;
            // log_sigmoid(x) = min(x,0) - log1p(exp(-|x|))  (matches jax.nn.log_sigmoid)
            lsp[i] = fminf(x, 0.0f) - log1pf(expf(-fabsf(x)));
        }
        *(float4*)&logitsT[(size_t)s * 128 + nb] = lg;
        *(float4*)&lsT[(size_t)s * 128 + nb] = ls;
    }
}

// ---------- K3: sequential DP over s (one wave, 2 rows/lane), walk, outputs ----------
__global__ __launch_bounds__(64) void k3_dp(
    const float* __restrict__ lsT, const float* __restrict__ logitsT,
    float* __restrict__ out)
{
    __shared__ unsigned takeW[128 * 65];   // [n][wordIdx], padded 65 -> 2-way conflicts only
    __shared__ int alignSh[128];
    const int lane = threadIdx.x;
    const int n0 = 2 * lane, n1 = n0 + 1;
    const bool isLast = (lane == 63);
    const float2* __restrict__ ls2 = (const float2*)lsT;  // element (s*64 + lane) = lsT[s][2l..2l+1]

    float p0 = NEGC, p1 = NEGC;
    unsigned u0 = 2047u - (unsigned)n0;   // s - n0  (decremented per step)
    unsigned u1 = u0 - 1u;                // s - n1
    unsigned w0 = 0u, w1 = 0u;

    auto step = [&](float2 lsv) {
        // nxt[n] = prev_col[n+1]; lane l needs p0 from lane l+1 -> DPP wave_shl1
        float nxt1 = __int_as_float(__builtin_amdgcn_update_dpp(
            0, __float_as_int(p0), 0x130 /*WAVE_SHL1*/, 0xf, 0xf, true));
        nxt1 = isLast ? 0.0f : nxt1;      // n==127: curr = ls + 0
        const float c0 = lsv.x + p1;
        const float c1 = lsv.y + nxt1;
        const unsigned t0 = (c0 >= p0) ? 1u : 0u;
        const unsigned t1 = (c1 >= p1) ? 1u : 0u;
        const float v0 = fmaxf(c0, p0);   // == take ? curr : prev
        const float v1 = fmaxf(c1, p1);
        p0 = (u0 <= 1920u) ? v0 : NEGC;   // in_range: 0 <= s-n <= S-N (unsigned wrap covers s<n)
        p1 = (u1 <= 1920u) ? v1 : NEGC;
        --u0; --u1;
        w0 = (w0 << 1) | t0;              // bit position = s & 31
        w1 = (w1 << 1) | t1;
    };

    float2 bufA[16], bufB[16];
    #pragma unroll
    for (int j = 0; j < 16; ++j) bufA[j] = ls2[(2047 - j) * 64 + lane];

    int wIdx = 63;
    for (int g = 0; g < 128; g += 2) {
        #pragma unroll
        for (int j = 0; j < 16; ++j) bufB[j] = ls2[(2047 - 16 * (g + 1) - j) * 64 + lane];
        #pragma unroll
        for (int j = 0; j < 16; ++j) step(bufA[j]);
        if (g + 2 < 128) {
            #pragma unroll
            for (int j = 0; j < 16; ++j) bufA[j] = ls2[(2047 - 16 * (g + 2) - j) * 64 + lane];
        }
        #pragma unroll
        for (int j = 0; j < 16; ++j) step(bufB[j]);
        takeW[n0 * 65 + wIdx] = w0;
        takeW[n1 * 65 + wIdx] = w1;
        w0 = 0u; w1 = 0u;
        --wIdx;
    }

    alignSh[n0] = 0;
    alignSh[n1] = 0;
    __syncthreads();

    // walk: align[n] = first s >= pos with take[n][s]; pos = align+1; stop if none
    if (lane == 0) {
        int pos = 0;
        for (int n = 0; n < 128; ++n) {
            const unsigned* row = &takeW[n * 65];
            int wi = pos >> 5;
            unsigned w = (pos < 2048) ? (row[wi] & (0xFFFFFFFFu << (pos & 31))) : 0u;
            while (w == 0u) {
                ++wi;
                if (wi >= 64) break;
                w = row[wi];
            }
            if (w == 0u) break;
            const int found = wi * 32 + __builtin_ctz(w);
            alignSh[n] = found;
            pos = found + 1;
        }
    }
    __syncthreads();

    const int a0 = alignSh[n0];
    const int a1 = alignSh[n1];
    // adj_matrix[S+n][align[n]] = 1
    out[(size_t)(2048 + n0) * 2176 + a0] = 1.0f;
    out[(size_t)(2048 + n1) * 2176 + a1] = 1.0f;
    // aggregated = mean(logits[n, align[n]])
    float sum = logitsT[(size_t)a0 * 128 + n0] + logitsT[(size_t)a1 * 128 + n1];
    #pragma unroll
    for (int off = 32; off >= 1; off >>= 1) sum += __shfl_down(sum, off);
    if (lane == 0) out[(size_t)2176 * 2176] = sum * (1.0f / 128.0f);
}

extern "C" void kernel_launch(void* const* d_in, const int* in_sizes, int n_in,
                              void* d_out, int out_size, void* d_ws, size_t ws_size,
                              hipStream_t stream)
{
    const float* seg = (const float*)d_in[0];   // [128][512]
    const float* vid = (const float*)d_in[1];   // [2048][512]
    const float* W1  = (const float*)d_in[2];   // [256][1024]
    const float* b1  = (const float*)d_in[3];   // [256]
    const float* W2  = (const float*)d_in[4];   // [256]
    const float* b2  = (const float*)d_in[5];   // [1]
    float* out = (float*)d_out;
    float* ws  = (float*)d_ws;

    float* A2      = ws;             // 128*256
    float* B2      = ws + 32768;     // 2048*256
    float* logitsT = ws + 557056;    // 2048*128, [s][n]
    float* lsT     = ws + 819200;    // 2048*128, [s][n]

    kzero_adj<<<dim3(4624), dim3(256), 0, stream>>>((float4*)out);
    k1_gemm<<<dim3(4, 34), dim3(256), 0, stream>>>(seg, vid, W1, b1, A2, B2);
    k2_logits<<<dim3(2, 32), dim3(256), 0, stream>>>(A2, B2, W2, b2, logitsT, lsT);
    k3_dp<<<dim3(1), dim3(64), 0, stream>>>(lsT, logitsT, out);
}

// Round 4
// 210.154 us; speedup vs baseline: 1.1288x; 1.1288x over previous
//
#include <hip/hip_runtime.h>
#include <math.h>

#define NEGC (-1000.0f)

// ---------- K1Z: blocks [0,136): GEMM  A2 = seg @ W1[:, :512]^T + b1 (128x256),
//                                       B2 = vid @ W1[:, 512:]^T     (2048x256)
//             blocks [136,4760): zero the adj matrix (2176*2176 floats) ----------
__global__ __launch_bounds__(256) void k1z_gemm(
    const float* __restrict__ seg, const float* __restrict__ vid,
    const float* __restrict__ W1, const float* __restrict__ b1,
    float* __restrict__ A2, float* __restrict__ B2, float4* __restrict__ out4)
{
    if (blockIdx.x >= 136) {
        const int i = (blockIdx.x - 136) * 256 + threadIdx.x;
        if (i < 1183744) out4[i] = make_float4(0.f, 0.f, 0.f, 0.f);
        return;
    }
    __shared__ float Xs[32][64];   // [kk][row]
    __shared__ float Ws[32][64];   // [kk][col]
    const int tid = threadIdx.x;
    const int tx = tid & 15, ty = tid >> 4;
    const int lr = tid >> 2;
    const int lk = (tid & 3) * 8;
    const int colBase = (blockIdx.x & 3) * 64;
    const int rowBase = (blockIdx.x >> 2) * 64;
    const bool isSeg = (rowBase < 128);
    const float* __restrict__ X = isSeg ? seg : vid;
    const int xRow = isSeg ? rowBase : (rowBase - 128);
    const int wOff = isSeg ? 0 : 512;

    float acc[4][4] = {};

    for (int k0 = 0; k0 < 512; k0 += 32) {
        const float* xp = X + (size_t)(xRow + lr) * 512 + (k0 + lk);
        const float4 xa = *(const float4*)xp;
        const float4 xb = *(const float4*)(xp + 4);
        const float* wp = W1 + (size_t)(colBase + lr) * 1024 + (wOff + k0 + lk);
        const float4 wa = *(const float4*)wp;
        const float4 wb = *(const float4*)(wp + 4);
        __syncthreads();
        Xs[lk + 0][lr] = xa.x; Xs[lk + 1][lr] = xa.y;
        Xs[lk + 2][lr] = xa.z; Xs[lk + 3][lr] = xa.w;
        Xs[lk + 4][lr] = xb.x; Xs[lk + 5][lr] = xb.y;
        Xs[lk + 6][lr] = xb.z; Xs[lk + 7][lr] = xb.w;
        Ws[lk + 0][lr] = wa.x; Ws[lk + 1][lr] = wa.y;
        Ws[lk + 2][lr] = wa.z; Ws[lk + 3][lr] = wa.w;
        Ws[lk + 4][lr] = wb.x; Ws[lk + 5][lr] = wb.y;
        Ws[lk + 6][lr] = wb.z; Ws[lk + 7][lr] = wb.w;
        __syncthreads();
        #pragma unroll
        for (int kk = 0; kk < 32; ++kk) {
            const float4 a4 = *(const float4*)&Xs[kk][4 * ty];
            const float4 b4 = *(const float4*)&Ws[kk][4 * tx];
            const float* a = (const float*)&a4;
            const float* b = (const float*)&b4;
            #pragma unroll
            for (int i = 0; i < 4; ++i)
                #pragma unroll
                for (int j = 0; j < 4; ++j)
                    acc[i][j] = fmaf(a[i], b[j], acc[i][j]);
        }
    }

    float* __restrict__ outp = (isSeg ? A2 : B2) + (size_t)xRow * 256;
    const int c = colBase + 4 * tx;
    #pragma unroll
    for (int i = 0; i < 4; ++i) {
        float4 v = make_float4(acc[i][0], acc[i][1], acc[i][2], acc[i][3]);
        if (isSeg) {
            v.x += b1[c + 0]; v.y += b1[c + 1]; v.z += b1[c + 2]; v.w += b1[c + 3];
        }
        *(float4*)(outp + (size_t)(4 * ty + i) * 256 + c) = v;
    }
}

// ---------- K2: logitsT[s][n] = sum_h relu(A2[n][h]+B2[s][h])*W2[h] + b2
//             lsT = log_sigmoid(logitsT) ----------
__global__ __launch_bounds__(256) void k2_logits(
    const float* __restrict__ A2, const float* __restrict__ B2,
    const float* __restrict__ W2, const float* __restrict__ b2p,
    float* __restrict__ logitsT, float* __restrict__ lsT)
{
    __shared__ float As[32][64];   // [kk][n]
    __shared__ float Bs[32][64];   // [kk][s]
    __shared__ float w2s[256];
    const int tid = threadIdx.x;
    const int tx = tid & 15, ty = tid >> 4;
    const int lr = tid >> 2;
    const int lk = (tid & 3) * 8;
    const int nBase = blockIdx.x * 64;
    const int sBase = blockIdx.y * 64;
    w2s[tid] = W2[tid];
    const float b2v = b2p[0];

    float acc[4][4] = {};   // [i:n][j:s]

    for (int k0 = 0; k0 < 256; k0 += 32) {
        const float* ap = A2 + (size_t)(nBase + lr) * 256 + (k0 + lk);
        const float4 aa = *(const float4*)ap;
        const float4 ab = *(const float4*)(ap + 4);
        const float* bp = B2 + (size_t)(sBase + lr) * 256 + (k0 + lk);
        const float4 ba = *(const float4*)bp;
        const float4 bb = *(const float4*)(bp + 4);
        __syncthreads();
        As[lk + 0][lr] = aa.x; As[lk + 1][lr] = aa.y;
        As[lk + 2][lr] = aa.z; As[lk + 3][lr] = aa.w;
        As[lk + 4][lr] = ab.x; As[lk + 5][lr] = ab.y;
        As[lk + 6][lr] = ab.z; As[lk + 7][lr] = ab.w;
        Bs[lk + 0][lr] = ba.x; Bs[lk + 1][lr] = ba.y;
        Bs[lk + 2][lr] = ba.z; Bs[lk + 3][lr] = ba.w;
        Bs[lk + 4][lr] = bb.x; Bs[lk + 5][lr] = bb.y;
        Bs[lk + 6][lr] = bb.z; Bs[lk + 7][lr] = bb.w;
        __syncthreads();
        #pragma unroll
        for (int kk = 0; kk < 32; ++kk) {
            const float w = w2s[k0 + kk];
            const float4 a4 = *(const float4*)&As[kk][4 * ty];
            const float4 b4 = *(const float4*)&Bs[kk][4 * tx];
            const float* a = (const float*)&a4;
            const float* b = (const float*)&b4;
            #pragma unroll
            for (int i = 0; i < 4; ++i)
                #pragma unroll
                for (int j = 0; j < 4; ++j)
                    acc[i][j] = fmaf(fmaxf(a[i] + b[j], 0.0f), w, acc[i][j]);
        }
    }

    const int nb = nBase + 4 * ty;
    #pragma unroll
    for (int j = 0; j < 4; ++j) {
        const int s = sBase + 4 * tx + j;
        float4 lg, ls;
        float* lgp = (float*)&lg;
        float* lsp = (float*)&ls;
        #pragma unroll
        for (int i = 0; i < 4; ++i) {
            const float x = acc[i][j] + b2v;
            lgp[i] = x;
            lsp[i] = fminf(x, 0.0f) - log1pf(expf(-fabsf(x)));
        }
        *(float4*)&logitsT[(size_t)s * 128 + nb] = lg;
        *(float4*)&lsT[(size_t)s * 128 + nb] = ls;
    }
}

// ---------- K3: sequential DP over s (one wave, 2 rows/lane), walk, outputs ----------
__global__ __launch_bounds__(64) void k3_dp(
    const float* __restrict__ lsT, const float* __restrict__ logitsT,
    float* __restrict__ out)
{
    __shared__ unsigned takeW[128 * 65];   // [n][wordIdx], 65-pad
    __shared__ int alignSh[128];
    const int lane = threadIdx.x;
    const int n0 = 2 * lane, n1 = n0 + 1;
    const float2* __restrict__ ls2 = (const float2*)lsT;  // (s*64+lane) = lsT[s][2l..2l+1]

    float p0 = NEGC, p1 = NEGC;
    unsigned u0 = 2047u - (unsigned)n0;   // s - n0 (head phase)
    unsigned u1 = u0 - 1u;                // s - n1
    unsigned w0 = 0u, w1 = 0u;

    // fast core: c0=ls0+p1; c1=ls1+nxt; w=(w<<1)|(c>=p); p=max(c,p)
    // dual carry regs (vcc + sgpr pair) decouple the two row chains.
    auto core = [&](float lx, float ly, float nx) {
        float c0, c1;
        unsigned long long cc;
        asm volatile(
            "v_add_f32 %[c0], %[lx], %[p1]\n\t"
            "v_add_f32 %[c1], %[ly], %[nx]\n\t"
            "v_cmp_ge_f32 vcc, %[c0], %[p0]\n\t"
            "v_cmp_ge_f32 %[cc], %[c1], %[p1]\n\t"
            "v_addc_co_u32 %[w0], vcc, %[w0], %[w0], vcc\n\t"
            "v_addc_co_u32 %[w1], %[cc], %[w1], %[w1], %[cc]\n\t"
            "v_max_f32 %[p0], %[c0], %[p0]\n\t"
            "v_max_f32 %[p1], %[c1], %[p1]\n\t"
            : [p0]"+v"(p0), [p1]"+v"(p1), [w0]"+v"(w0), [w1]"+v"(w1),
              [c0]"=&v"(c0), [c1]"=&v"(c1), [cc]"=&s"(cc)
            : [lx]"v"(lx), [ly]"v"(ly), [nx]"v"(nx)
            : "vcc");
    };

    auto stepF = [&](float2 lsv) {        // in-band: no range masking needed
        // nxt[n]=prev[n+1]; wave_shl1 + bound_ctrl: lane63 gets 0 (= n==127 case)
        float nxt1 = __int_as_float(__builtin_amdgcn_update_dpp(
            0, __float_as_int(p0), 0x130 /*WAVE_SHL1*/, 0xf, 0xf, true));
        core(lsv.x, lsv.y, nxt1);
    };
    auto stepM = [&](float2 lsv) {        // masked (head/tail)
        float nxt1 = __int_as_float(__builtin_amdgcn_update_dpp(
            0, __float_as_int(p0), 0x130, 0xf, 0xf, true));
        core(lsv.x, lsv.y, nxt1);
        p0 = (u0 <= 1920u) ? p0 : NEGC;   // 0 <= s-n <= 1920 (wrap covers s<n)
        p1 = (u1 <= 1920u) ? p1 : NEGC;
        --u0; --u1;
    };

    float2 bufA[16], bufB[16];
    #pragma unroll
    for (int j = 0; j < 16; ++j) bufA[j] = ls2[(2047 - j) * 64 + lane];

    int wIdx = 63;
    for (int g = 0; g < 128; g += 2) {
        if (wIdx == 3) {                  // tail entry: reset u = s - n at s=127
            u0 = (unsigned)(127 - n0);
            u1 = (unsigned)(127 - n1);
        }
        const bool masked = (wIdx >= 60) || (wIdx <= 3);
        #pragma unroll
        for (int j = 0; j < 16; ++j) bufB[j] = ls2[(2047 - 16 * (g + 1) - j) * 64 + lane];
        if (masked) {
            #pragma unroll
            for (int j = 0; j < 16; ++j) stepM(bufA[j]);
        } else {
            #pragma unroll
            for (int j = 0; j < 16; ++j) stepF(bufA[j]);
        }
        if (g + 2 < 128) {
            #pragma unroll
            for (int j = 0; j < 16; ++j) bufA[j] = ls2[(2047 - 16 * (g + 2) - j) * 64 + lane];
        }
        if (masked) {
            #pragma unroll
            for (int j = 0; j < 16; ++j) stepM(bufB[j]);
        } else {
            #pragma unroll
            for (int j = 0; j < 16; ++j) stepF(bufB[j]);
        }
        takeW[n0 * 65 + wIdx] = w0;
        takeW[n1 * 65 + wIdx] = w1;
        w0 = 0u; w1 = 0u;
        --wIdx;
    }

    alignSh[n0] = 0;
    alignSh[n1] = 0;
    __syncthreads();

    // wave-parallel walk: lane holds word 'lane' of row n; ballot -> first set bit
    int pos = 0;
    for (int n = 0; n < 128; ++n) {
        unsigned w = takeW[n * 65 + lane];
        const int wi0 = pos >> 5;
        if (lane < wi0) w = 0u;
        else if (lane == wi0) w &= (0xFFFFFFFFu << (pos & 31));
        const unsigned long long m = __ballot(w != 0u);
        if (m == 0ull) break;             // uniform
        const int fl = __builtin_ctzll(m);
        const unsigned fw = (unsigned)__builtin_amdgcn_readlane((int)w, fl);
        const int s = fl * 32 + __builtin_ctz(fw);
        if (lane == 0) alignSh[n] = s;
        pos = s + 1;
    }
    __syncthreads();

    const int a0 = alignSh[n0];
    const int a1 = alignSh[n1];
    out[(size_t)(2048 + n0) * 2176 + a0] = 1.0f;
    out[(size_t)(2048 + n1) * 2176 + a1] = 1.0f;
    float sum = logitsT[(size_t)a0 * 128 + n0] + logitsT[(size_t)a1 * 128 + n1];
    #pragma unroll
    for (int off = 32; off >= 1; off >>= 1) sum += __shfl_down(sum, off);
    if (lane == 0) out[(size_t)2176 * 2176] = sum * (1.0f / 128.0f);
}

extern "C" void kernel_launch(void* const* d_in, const int* in_sizes, int n_in,
                              void* d_out, int out_size, void* d_ws, size_t ws_size,
                              hipStream_t stream)
{
    const float* seg = (const float*)d_in[0];   // [128][512]
    const float* vid = (const float*)d_in[1];   // [2048][512]
    const float* W1  = (const float*)d_in[2];   // [256][1024]
    const float* b1  = (const float*)d_in[3];   // [256]
    const float* W2  = (const float*)d_in[4];   // [256]
    const float* b2  = (const float*)d_in[5];   // [1]
    float* out = (float*)d_out;
    float* ws  = (float*)d_ws;

    float* A2      = ws;             // 128*256
    float* B2      = ws + 32768;     // 2048*256
    float* logitsT = ws + 557056;    // 2048*128, [s][n]
    float* lsT     = ws + 819200;    // 2048*128, [s][n]

    k1z_gemm<<<dim3(4760), dim3(256), 0, stream>>>(seg, vid, W1, b1, A2, B2, (float4*)out);
    k2_logits<<<dim3(2, 32), dim3(256), 0, stream>>>(A2, B2, W2, b2, logitsT, lsT);
    k3_dp<<<dim3(1), dim3(64), 0, stream>>>(lsT, logitsT, out);
}

// Round 5
// 197.056 us; speedup vs baseline: 1.2039x; 1.0665x over previous
//
#include <hip/hip_runtime.h>
#include <math.h>

#define NEGC (-1000.0f)

// ---------- K1Z: blocks [0,136): GEMM  A2 = seg @ W1[:, :512]^T + b1 (128x256),
//                                       B2 = vid @ W1[:, 512:]^T     (2048x256)
//             blocks [136,4760): zero the adj matrix (2176*2176 floats) ----------
__global__ __launch_bounds__(256) void k1z_gemm(
    const float* __restrict__ seg, const float* __restrict__ vid,
    const float* __restrict__ W1, const float* __restrict__ b1,
    float* __restrict__ A2, float* __restrict__ B2, float4* __restrict__ out4)
{
    if (blockIdx.x >= 136) {
        const int i = (blockIdx.x - 136) * 256 + threadIdx.x;
        if (i < 1183744) out4[i] = make_float4(0.f, 0.f, 0.f, 0.f);
        return;
    }
    __shared__ float Xs[32][64];   // [kk][row]
    __shared__ float Ws[32][64];   // [kk][col]
    const int tid = threadIdx.x;
    const int tx = tid & 15, ty = tid >> 4;
    const int lr = tid >> 2;
    const int lk = (tid & 3) * 8;
    const int colBase = (blockIdx.x & 3) * 64;
    const int rowBase = (blockIdx.x >> 2) * 64;
    const bool isSeg = (rowBase < 128);
    const float* __restrict__ X = isSeg ? seg : vid;
    const int xRow = isSeg ? rowBase : (rowBase - 128);
    const int wOff = isSeg ? 0 : 512;

    float acc[4][4] = {};

    for (int k0 = 0; k0 < 512; k0 += 32) {
        const float* xp = X + (size_t)(xRow + lr) * 512 + (k0 + lk);
        const float4 xa = *(const float4*)xp;
        const float4 xb = *(const float4*)(xp + 4);
        const float* wp = W1 + (size_t)(colBase + lr) * 1024 + (wOff + k0 + lk);
        const float4 wa = *(const float4*)wp;
        const float4 wb = *(const float4*)(wp + 4);
        __syncthreads();
        Xs[lk + 0][lr] = xa.x; Xs[lk + 1][lr] = xa.y;
        Xs[lk + 2][lr] = xa.z; Xs[lk + 3][lr] = xa.w;
        Xs[lk + 4][lr] = xb.x; Xs[lk + 5][lr] = xb.y;
        Xs[lk + 6][lr] = xb.z; Xs[lk + 7][lr] = xb.w;
        Ws[lk + 0][lr] = wa.x; Ws[lk + 1][lr] = wa.y;
        Ws[lk + 2][lr] = wa.z; Ws[lk + 3][lr] = wa.w;
        Ws[lk + 4][lr] = wb.x; Ws[lk + 5][lr] = wb.y;
        Ws[lk + 6][lr] = wb.z; Ws[lk + 7][lr] = wb.w;
        __syncthreads();
        #pragma unroll
        for (int kk = 0; kk < 32; ++kk) {
            const float4 a4 = *(const float4*)&Xs[kk][4 * ty];
            const float4 b4 = *(const float4*)&Ws[kk][4 * tx];
            const float* a = (const float*)&a4;
            const float* b = (const float*)&b4;
            #pragma unroll
            for (int i = 0; i < 4; ++i)
                #pragma unroll
                for (int j = 0; j < 4; ++j)
                    acc[i][j] = fmaf(a[i], b[j], acc[i][j]);
        }
    }

    float* __restrict__ outp = (isSeg ? A2 : B2) + (size_t)xRow * 256;
    const int c = colBase + 4 * tx;
    #pragma unroll
    for (int i = 0; i < 4; ++i) {
        float4 v = make_float4(acc[i][0], acc[i][1], acc[i][2], acc[i][3]);
        if (isSeg) {
            v.x += b1[c + 0]; v.y += b1[c + 1]; v.z += b1[c + 2]; v.w += b1[c + 3];
        }
        *(float4*)(outp + (size_t)(4 * ty + i) * 256 + c) = v;
    }
}

// ---------- K2: logitsT[s][n] = sum_h relu(A2[n][h]+B2[s][h])*W2[h] + b2
//             lsT = log_sigmoid(logitsT) ----------
__global__ __launch_bounds__(256) void k2_logits(
    const float* __restrict__ A2, const float* __restrict__ B2,
    const float* __restrict__ W2, const float* __restrict__ b2p,
    float* __restrict__ logitsT, float* __restrict__ lsT)
{
    __shared__ float As[32][64];   // [kk][n]
    __shared__ float Bs[32][64];   // [kk][s]
    __shared__ float w2s[256];
    const int tid = threadIdx.x;
    const int tx = tid & 15, ty = tid >> 4;
    const int lr = tid >> 2;
    const int lk = (tid & 3) * 8;
    const int nBase = blockIdx.x * 64;
    const int sBase = blockIdx.y * 64;
    w2s[tid] = W2[tid];
    const float b2v = b2p[0];

    float acc[4][4] = {};   // [i:n][j:s]

    for (int k0 = 0; k0 < 256; k0 += 32) {
        const float* ap = A2 + (size_t)(nBase + lr) * 256 + (k0 + lk);
        const float4 aa = *(const float4*)ap;
        const float4 ab = *(const float4*)(ap + 4);
        const float* bp = B2 + (size_t)(sBase + lr) * 256 + (k0 + lk);
        const float4 ba = *(const float4*)bp;
        const float4 bb = *(const float4*)(bp + 4);
        __syncthreads();
        As[lk + 0][lr] = aa.x; As[lk + 1][lr] = aa.y;
        As[lk + 2][lr] = aa.z; As[lk + 3][lr] = aa.w;
        As[lk + 4][lr] = ab.x; As[lk + 5][lr] = ab.y;
        As[lk + 6][lr] = ab.z; As[lk + 7][lr] = ab.w;
        Bs[lk + 0][lr] = ba.x; Bs[lk + 1][lr] = ba.y;
        Bs[lk + 2][lr] = ba.z; Bs[lk + 3][lr] = ba.w;
        Bs[lk + 4][lr] = bb.x; Bs[lk + 5][lr] = bb.y;
        Bs[lk + 6][lr] = bb.z; Bs[lk + 7][lr] = bb.w;
        __syncthreads();
        #pragma unroll
        for (int kk = 0; kk < 32; ++kk) {
            const float w = w2s[k0 + kk];
            const float4 a4 = *(const float4*)&As[kk][4 * ty];
            const float4 b4 = *(const float4*)&Bs[kk][4 * tx];
            const float* a = (const float*)&a4;
            const float* b = (const float*)&b4;
            #pragma unroll
            for (int i = 0; i < 4; ++i)
                #pragma unroll
                for (int j = 0; j < 4; ++j)
                    acc[i][j] = fmaf(fmaxf(a[i] + b[j], 0.0f), w, acc[i][j]);
        }
    }

    const int nb = nBase + 4 * ty;
    #pragma unroll
    for (int j = 0; j < 4; ++j) {
        const int s = sBase + 4 * tx + j;
        float4 lg, ls;
        float* lgp = (float*)&lg;
        float* lsp = (float*)&ls;
        #pragma unroll
        for (int i = 0; i < 4; ++i) {
            const float x = acc[i][j] + b2v;
            lgp[i] = x;
            lsp[i] = fminf(x, 0.0f) - log1pf(expf(-fabsf(x)));
        }
        *(float4*)&logitsT[(size_t)s * 128 + nb] = lg;
        *(float4*)&lsT[(size_t)s * 128 + nb] = ls;
    }
}

// ---------- K3: sequential DP over s (one wave, 2 rows/lane), walk, outputs.
// Depth-3 sub-group prefetch (48 steps ~ >900 cyc slack) to hide L3/HBM latency. ----------
__global__ __launch_bounds__(64) void k3_dp(
    const float* __restrict__ lsT, const float* __restrict__ logitsT,
    float* __restrict__ out)
{
    __shared__ unsigned takeW[128 * 65];   // [n][wordIdx], 65-pad
    __shared__ int alignSh[128];
    const int lane = threadIdx.x;
    const int n0 = 2 * lane, n1 = n0 + 1;
    const float2* __restrict__ ls2 = (const float2*)lsT;  // (s*64+lane) = lsT[s][2l..2l+1]

    float p0 = NEGC, p1 = NEGC;
    unsigned u0 = 2047u - (unsigned)n0;   // s - n0 (head phase)
    unsigned u1 = u0 - 1u;                // s - n1
    unsigned w0 = 0u, w1 = 0u;

    // fast core: c0=ls0+p1; c1=ls1+nxt; w=(w<<1)|(c>=p); p=max(c,p)
    auto core = [&](float lx, float ly, float nx) {
        float c0, c1;
        unsigned long long cc;
        asm volatile(
            "v_add_f32 %[c0], %[lx], %[p1]\n\t"
            "v_add_f32 %[c1], %[ly], %[nx]\n\t"
            "v_cmp_ge_f32 vcc, %[c0], %[p0]\n\t"
            "v_cmp_ge_f32 %[cc], %[c1], %[p1]\n\t"
            "v_addc_co_u32 %[w0], vcc, %[w0], %[w0], vcc\n\t"
            "v_addc_co_u32 %[w1], %[cc], %[w1], %[w1], %[cc]\n\t"
            "v_max_f32 %[p0], %[c0], %[p0]\n\t"
            "v_max_f32 %[p1], %[c1], %[p1]\n\t"
            : [p0]"+v"(p0), [p1]"+v"(p1), [w0]"+v"(w0), [w1]"+v"(w1),
              [c0]"=&v"(c0), [c1]"=&v"(c1), [cc]"=&s"(cc)
            : [lx]"v"(lx), [ly]"v"(ly), [nx]"v"(nx)
            : "vcc");
    };

    auto stepF = [&](float2 lsv) {        // in-band: no range masking needed
        float nxt1 = __int_as_float(__builtin_amdgcn_update_dpp(
            0, __float_as_int(p0), 0x130 /*WAVE_SHL1*/, 0xf, 0xf, true));
        core(lsv.x, lsv.y, nxt1);
    };
    auto stepM = [&](float2 lsv) {        // masked (head/tail)
        float nxt1 = __int_as_float(__builtin_amdgcn_update_dpp(
            0, __float_as_int(p0), 0x130, 0xf, 0xf, true));
        core(lsv.x, lsv.y, nxt1);
        p0 = (u0 <= 1920u) ? p0 : NEGC;   // 0 <= s-n <= 1920 (wrap covers s<n)
        p1 = (u1 <= 1920u) ? p1 : NEGC;
        --u0; --u1;
    };

    // 4 register buffers of 16 float2; all indices compile-time (no scratch).
    float2 b0[16], b1[16], b2[16], b3[16];
#define LOADG(B, H) { _Pragma("unroll") \
    for (int j = 0; j < 16; ++j) B[j] = ls2[(size_t)((2047 - 16 * (H) - j) * 64 + lane)]; }
#define STEPS_F(B) { _Pragma("unroll") for (int j = 0; j < 16; ++j) stepF(B[j]); }
#define STEPS_M(B) { _Pragma("unroll") for (int j = 0; j < 16; ++j) stepM(B[j]); }
#define FLUSH { takeW[n0 * 65 + wIdx] = w0; takeW[n1 * 65 + wIdx] = w1; \
                w0 = 0u; w1 = 0u; --wIdx; }
#define BODY(SM) \
    LOADG(b3, h + 3); \
    SM(b0); \
    if (h + 4 < 128) LOADG(b0, h + 4); \
    SM(b1); FLUSH; \
    if (h + 5 < 128) LOADG(b1, h + 5); \
    SM(b2); \
    if (h + 6 < 128) LOADG(b2, h + 6); \
    SM(b3); FLUSH;

    LOADG(b0, 0) LOADG(b1, 1) LOADG(b2, 2)
    int wIdx = 63;
    // head: sub-groups 0..7 (words 63..60, s 2047..1920) — masked
    for (int h = 0; h < 8; h += 4) { BODY(STEPS_M) }
    // mid: sub-groups 8..119 (words 59..4) — in-band, no masking
    for (int h = 8; h < 120; h += 4) { BODY(STEPS_F) }
    // tail: sub-groups 120..127 (words 3..0, s 127..0) — masked
    u0 = (unsigned)(127 - n0);
    u1 = u0 - 1u;
    for (int h = 120; h < 128; h += 4) { BODY(STEPS_M) }
#undef BODY
#undef FLUSH
#undef STEPS_M
#undef STEPS_F
#undef LOADG

    alignSh[n0] = 0;
    alignSh[n1] = 0;
    __syncthreads();

    // wave-parallel walk: lane holds word 'lane' of row n; ballot -> first set bit
    int pos = 0;
    for (int n = 0; n < 128; ++n) {
        unsigned w = takeW[n * 65 + lane];
        const int wi0 = pos >> 5;
        if (lane < wi0) w = 0u;
        else if (lane == wi0) w &= (0xFFFFFFFFu << (pos & 31));
        const unsigned long long m = __ballot(w != 0u);
        if (m == 0ull) break;             // uniform
        const int fl = __builtin_ctzll(m);
        const unsigned fw = (unsigned)__builtin_amdgcn_readlane((int)w, fl);
        const int s = fl * 32 + __builtin_ctz(fw);
        if (lane == 0) alignSh[n] = s;
        pos = s + 1;
    }
    __syncthreads();

    const int a0 = alignSh[n0];
    const int a1 = alignSh[n1];
    out[(size_t)(2048 + n0) * 2176 + a0] = 1.0f;
    out[(size_t)(2048 + n1) * 2176 + a1] = 1.0f;
    float sum = logitsT[(size_t)a0 * 128 + n0] + logitsT[(size_t)a1 * 128 + n1];
    #pragma unroll
    for (int off = 32; off >= 1; off >>= 1) sum += __shfl_down(sum, off);
    if (lane == 0) out[(size_t)2176 * 2176] = sum * (1.0f / 128.0f);
}

extern "C" void kernel_launch(void* const* d_in, const int* in_sizes, int n_in,
                              void* d_out, int out_size, void* d_ws, size_t ws_size,
                              hipStream_t stream)
{
    const float* seg = (const float*)d_in[0];   // [128][512]
    const float* vid = (const float*)d_in[1];   // [2048][512]
    const float* W1  = (const float*)d_in[2];   // [256][1024]
    const float* b1  = (const float*)d_in[3];   // [256]
    const float* W2  = (const float*)d_in[4];   // [256]
    const float* b2  = (const float*)d_in[5];   // [1]
    float* out = (float*)d_out;
    float* ws  = (float*)d_ws;

    float* A2      = ws;             // 128*256
    float* B2      = ws + 32768;     // 2048*256
    float* logitsT = ws + 557056;    // 2048*128, [s][n]
    float* lsT     = ws + 819200;    // 2048*128, [s][n]

    k1z_gemm<<<dim3(4760), dim3(256), 0, stream>>>(seg, vid, W1, b1, A2, B2, (float4*)out);
    k2_logits<<<dim3(2, 32), dim3(256), 0, stream>>>(A2, B2, W2, b2, logitsT, lsT);
    k3_dp<<<dim3(1), dim3(64), 0, stream>>>(lsT, logitsT, out);
}

// Round 6
// 193.669 us; speedup vs baseline: 1.2249x; 1.0175x over previous
//
#include <hip/hip_runtime.h>
#include <math.h>

#define NEGC (-1000.0f)

// ---------- K1Z: blocks [0,136): GEMM  A2 = seg @ W1[:, :512]^T + b1 (128x256),
//                                       B2 = vid @ W1[:, 512:]^T     (2048x256)
//             blocks [136,4760): zero the adj matrix (2176*2176 floats) ----------
__global__ __launch_bounds__(256) void k1z_gemm(
    const float* __restrict__ seg, const float* __restrict__ vid,
    const float* __restrict__ W1, const float* __restrict__ b1,
    float* __restrict__ A2, float* __restrict__ B2, float4* __restrict__ out4)
{
    if (blockIdx.x >= 136) {
        const int i = (blockIdx.x - 136) * 256 + threadIdx.x;
        if (i < 1183744) out4[i] = make_float4(0.f, 0.f, 0.f, 0.f);
        return;
    }
    __shared__ float Xs[32][64];   // [kk][row]
    __shared__ float Ws[32][64];   // [kk][col]
    const int tid = threadIdx.x;
    const int tx = tid & 15, ty = tid >> 4;
    const int lr = tid >> 2;
    const int lk = (tid & 3) * 8;
    const int colBase = (blockIdx.x & 3) * 64;
    const int rowBase = (blockIdx.x >> 2) * 64;
    const bool isSeg = (rowBase < 128);
    const float* __restrict__ X = isSeg ? seg : vid;
    const int xRow = isSeg ? rowBase : (rowBase - 128);
    const int wOff = isSeg ? 0 : 512;

    float acc[4][4] = {};

    for (int k0 = 0; k0 < 512; k0 += 32) {
        const float* xp = X + (size_t)(xRow + lr) * 512 + (k0 + lk);
        const float4 xa = *(const float4*)xp;
        const float4 xb = *(const float4*)(xp + 4);
        const float* wp = W1 + (size_t)(colBase + lr) * 1024 + (wOff + k0 + lk);
        const float4 wa = *(const float4*)wp;
        const float4 wb = *(const float4*)(wp + 4);
        __syncthreads();
        Xs[lk + 0][lr] = xa.x; Xs[lk + 1][lr] = xa.y;
        Xs[lk + 2][lr] = xa.z; Xs[lk + 3][lr] = xa.w;
        Xs[lk + 4][lr] = xb.x; Xs[lk + 5][lr] = xb.y;
        Xs[lk + 6][lr] = xb.z; Xs[lk + 7][lr] = xb.w;
        Ws[lk + 0][lr] = wa.x; Ws[lk + 1][lr] = wa.y;
        Ws[lk + 2][lr] = wa.z; Ws[lk + 3][lr] = wa.w;
        Ws[lk + 4][lr] = wb.x; Ws[lk + 5][lr] = wb.y;
        Ws[lk + 6][lr] = wb.z; Ws[lk + 7][lr] = wb.w;
        __syncthreads();
        #pragma unroll
        for (int kk = 0; kk < 32; ++kk) {
            const float4 a4 = *(const float4*)&Xs[kk][4 * ty];
            const float4 b4 = *(const float4*)&Ws[kk][4 * tx];
            const float* a = (const float*)&a4;
            const float* b = (const float*)&b4;
            #pragma unroll
            for (int i = 0; i < 4; ++i)
                #pragma unroll
                for (int j = 0; j < 4; ++j)
                    acc[i][j] = fmaf(a[i], b[j], acc[i][j]);
        }
    }

    float* __restrict__ outp = (isSeg ? A2 : B2) + (size_t)xRow * 256;
    const int c = colBase + 4 * tx;
    #pragma unroll
    for (int i = 0; i < 4; ++i) {
        float4 v = make_float4(acc[i][0], acc[i][1], acc[i][2], acc[i][3]);
        if (isSeg) {
            v.x += b1[c + 0]; v.y += b1[c + 1]; v.z += b1[c + 2]; v.w += b1[c + 3];
        }
        *(float4*)(outp + (size_t)(4 * ty + i) * 256 + c) = v;
    }
}

// ---------- K2: logitsT[s][n] (old layout, for final gather) and
//   lsPK packed layout [s/2][n][2]: lsPK[s2*256 + 2n + (s&1)] = log_sigmoid(logits[n][s])
//   so one float4 at (s2*256+4l) = {ls[2s2][2l], ls[2s2+1][2l], ls[2s2][2l+1], ls[2s2+1][2l+1]} ----------
__global__ __launch_bounds__(256) void k2_logits(
    const float* __restrict__ A2, const float* __restrict__ B2,
    const float* __restrict__ W2, const float* __restrict__ b2p,
    float* __restrict__ logitsT, float* __restrict__ lsPK)
{
    __shared__ float As[32][64];   // [kk][n]
    __shared__ float Bs[32][64];   // [kk][s]
    __shared__ float w2s[256];
    const int tid = threadIdx.x;
    const int tx = tid & 15, ty = tid >> 4;
    const int lr = tid >> 2;
    const int lk = (tid & 3) * 8;
    const int nBase = blockIdx.x * 64;
    const int sBase = blockIdx.y * 64;
    w2s[tid] = W2[tid];
    const float b2v = b2p[0];

    float acc[4][4] = {};   // [i:n][j:s]

    for (int k0 = 0; k0 < 256; k0 += 32) {
        const float* ap = A2 + (size_t)(nBase + lr) * 256 + (k0 + lk);
        const float4 aa = *(const float4*)ap;
        const float4 ab = *(const float4*)(ap + 4);
        const float* bp = B2 + (size_t)(sBase + lr) * 256 + (k0 + lk);
        const float4 ba = *(const float4*)bp;
        const float4 bb = *(const float4*)(bp + 4);
        __syncthreads();
        As[lk + 0][lr] = aa.x; As[lk + 1][lr] = aa.y;
        As[lk + 2][lr] = aa.z; As[lk + 3][lr] = aa.w;
        As[lk + 4][lr] = ab.x; As[lk + 5][lr] = ab.y;
        As[lk + 6][lr] = ab.z; As[lk + 7][lr] = ab.w;
        Bs[lk + 0][lr] = ba.x; Bs[lk + 1][lr] = ba.y;
        Bs[lk + 2][lr] = ba.z; Bs[lk + 3][lr] = ba.w;
        Bs[lk + 4][lr] = bb.x; Bs[lk + 5][lr] = bb.y;
        Bs[lk + 6][lr] = bb.z; Bs[lk + 7][lr] = bb.w;
        __syncthreads();
        #pragma unroll
        for (int kk = 0; kk < 32; ++kk) {
            const float w = w2s[k0 + kk];
            const float4 a4 = *(const float4*)&As[kk][4 * ty];
            const float4 b4 = *(const float4*)&Bs[kk][4 * tx];
            const float* a = (const float*)&a4;
            const float* b = (const float*)&b4;
            #pragma unroll
            for (int i = 0; i < 4; ++i)
                #pragma unroll
                for (int j = 0; j < 4; ++j)
                    acc[i][j] = fmaf(fmaxf(a[i] + b[j], 0.0f), w, acc[i][j]);
        }
    }

    const int nb = nBase + 4 * ty;
    const int s0 = sBase + 4 * tx;          // even
    float lsv[4][4];                        // [j:s-offset][i:n-offset]
    #pragma unroll
    for (int j = 0; j < 4; ++j) {
        const int s = s0 + j;
        float4 lg;
        float* lgp = (float*)&lg;
        #pragma unroll
        for (int i = 0; i < 4; ++i) {
            const float x = acc[i][j] + b2v;
            lgp[i] = x;
            lsv[j][i] = fminf(x, 0.0f) - log1pf(expf(-fabsf(x)));
        }
        *(float4*)&logitsT[(size_t)s * 128 + nb] = lg;
    }
    #pragma unroll
    for (int m = 0; m < 2; ++m) {           // two s-pairs
        const size_t base = (size_t)(s0 / 2 + m) * 256 + 2 * nb;
        #pragma unroll
        for (int q = 0; q < 2; ++q) {       // two n-pairs
            float4 v = make_float4(lsv[2 * m][2 * q],     lsv[2 * m + 1][2 * q],
                                   lsv[2 * m][2 * q + 1], lsv[2 * m + 1][2 * q + 1]);
            *(float4*)&lsPK[base + 4 * q] = v;
        }
    }
}

// ---------- K3: sequential DP over s (one wave, 2 rows/lane), walk, outputs.
// Packed dwordx4 loads (2 s-steps each), 8-buffer rotation, depth-8 prefetch
// (~32 loads in flight, >1200 cyc slack > 900 cyc HBM latency). ----------
__global__ __launch_bounds__(64, 1) void k3_dp(
    const float* __restrict__ lsPK, const float* __restrict__ logitsT,
    float* __restrict__ out)
{
    __shared__ unsigned takeW[128 * 65];   // [n][wordIdx], 65-pad
    __shared__ int alignSh[128];
    const int lane = threadIdx.x;
    const int n0 = 2 * lane, n1 = n0 + 1;
    const float4* __restrict__ ls4 = (const float4*)lsPK; // ls4[s2*64+l] = {lo.n0, hi.n0, lo.n1, hi.n1}

    float p0 = NEGC, p1 = NEGC;
    unsigned u0 = 2047u - (unsigned)n0;   // s - n0 (head phase)
    unsigned u1 = u0 - 1u;                // s - n1
    unsigned w0 = 0u, w1 = 0u;

    // fast core: c0=lx+p1; c1=ly+nxt; w=(w<<1)|(c>=p); p=max(c,p)
    auto core = [&](float lx, float ly, float nx) {
        float c0, c1;
        unsigned long long cc;
        asm volatile(
            "v_add_f32 %[c0], %[lx], %[p1]\n\t"
            "v_add_f32 %[c1], %[ly], %[nx]\n\t"
            "v_cmp_ge_f32 vcc, %[c0], %[p0]\n\t"
            "v_cmp_ge_f32 %[cc], %[c1], %[p1]\n\t"
            "v_addc_co_u32 %[w0], vcc, %[w0], %[w0], vcc\n\t"
            "v_addc_co_u32 %[w1], %[cc], %[w1], %[w1], %[cc]\n\t"
            "v_max_f32 %[p0], %[c0], %[p0]\n\t"
            "v_max_f32 %[p1], %[c1], %[p1]\n\t"
            : [p0]"+v"(p0), [p1]"+v"(p1), [w0]"+v"(w0), [w1]"+v"(w1),
              [c0]"=&v"(c0), [c1]"=&v"(c1), [cc]"=&s"(cc)
            : [lx]"v"(lx), [ly]"v"(ly), [nx]"v"(nx)
            : "vcc");
    };

    auto stepF = [&](float lx, float ly) { // in-band: no range masking
        float nxt1 = __int_as_float(__builtin_amdgcn_update_dpp(
            0, __float_as_int(p0), 0x130 /*WAVE_SHL1*/, 0xf, 0xf, true));
        core(lx, ly, nxt1);
    };
    auto stepM = [&](float lx, float ly) { // masked (head/tail)
        float nxt1 = __int_as_float(__builtin_amdgcn_update_dpp(
            0, __float_as_int(p0), 0x130, 0xf, 0xf, true));
        core(lx, ly, nxt1);
        p0 = (u0 <= 1920u) ? p0 : NEGC;   // 0 <= s-n <= 1920 (wrap covers s<n)
        p1 = (u1 <= 1920u) ? p1 : NEGC;
        --u0; --u1;
    };

    // 8 rotating buffers of 4 float4 (8 s-steps each); all indices compile-time.
    float4 B0[4], B1[4], B2[4], B3[4], B4[4], B5[4], B6[4], B7[4];
#define LOADG(B, H) { _Pragma("unroll") \
    for (int j = 0; j < 4; ++j) B[j] = ls4[(size_t)((1023 - 4 * (H) - j) * 64 + lane)]; }
#define STEPS_F(B) { _Pragma("unroll") \
    for (int j = 0; j < 4; ++j) { stepF(B[j].y, B[j].w); stepF(B[j].x, B[j].z); } }
#define STEPS_M(B) { _Pragma("unroll") \
    for (int j = 0; j < 4; ++j) { stepM(B[j].y, B[j].w); stepM(B[j].x, B[j].z); } }
#define FLUSH { takeW[n0 * 65 + wIdx] = w0; takeW[n1 * 65 + wIdx] = w1; \
                w0 = 0u; w1 = 0u; --wIdx; }
#define BODY(SM) \
    SM(B0); if (h +  8 < 256) LOADG(B0, h +  8); \
    SM(B1); if (h +  9 < 256) LOADG(B1, h +  9); \
    SM(B2); if (h + 10 < 256) LOADG(B2, h + 10); \
    SM(B3); FLUSH; if (h + 11 < 256) LOADG(B3, h + 11); \
    SM(B4); if (h + 12 < 256) LOADG(B4, h + 12); \
    SM(B5); if (h + 13 < 256) LOADG(B5, h + 13); \
    SM(B6); if (h + 14 < 256) LOADG(B6, h + 14); \
    SM(B7); FLUSH; if (h + 15 < 256) LOADG(B7, h + 15);

    LOADG(B0, 0) LOADG(B1, 1) LOADG(B2, 2) LOADG(B3, 3)
    LOADG(B4, 4) LOADG(B5, 5) LOADG(B6, 6) LOADG(B7, 7)
    int wIdx = 63;
    // head: sub-groups 0..15 (s 2047..1920) — masked
    for (int h = 0; h < 16; h += 8) { BODY(STEPS_M) }
    // mid: sub-groups 16..239 (s 1919..128) — in-band
    for (int h = 16; h < 240; h += 8) { BODY(STEPS_F) }
    // tail: sub-groups 240..255 (s 127..0) — masked; reset u = s - n at s=127
    u0 = (unsigned)(127 - n0);
    u1 = u0 - 1u;
    for (int h = 240; h < 256; h += 8) { BODY(STEPS_M) }
#undef BODY
#undef FLUSH
#undef STEPS_M
#undef STEPS_F
#undef LOADG

    alignSh[n0] = 0;
    alignSh[n1] = 0;
    __syncthreads();

    // wave-parallel walk: lane holds word 'lane' of row n; ballot -> first set bit
    int pos = 0;
    for (int n = 0; n < 128; ++n) {
        unsigned w = takeW[n * 65 + lane];
        const int wi0 = pos >> 5;
        if (lane < wi0) w = 0u;
        else if (lane == wi0) w &= (0xFFFFFFFFu << (pos & 31));
        const unsigned long long m = __ballot(w != 0u);
        if (m == 0ull) break;             // uniform
        const int fl = __builtin_ctzll(m);
        const unsigned fw = (unsigned)__builtin_amdgcn_readlane((int)w, fl);
        const int s = fl * 32 + __builtin_ctz(fw);
        if (lane == 0) alignSh[n] = s;
        pos = s + 1;
    }
    __syncthreads();

    const int a0 = alignSh[n0];
    const int a1 = alignSh[n1];
    out[(size_t)(2048 + n0) * 2176 + a0] = 1.0f;
    out[(size_t)(2048 + n1) * 2176 + a1] = 1.0f;
    float sum = logitsT[(size_t)a0 * 128 + n0] + logitsT[(size_t)a1 * 128 + n1];
    #pragma unroll
    for (int off = 32; off >= 1; off >>= 1) sum += __shfl_down(sum, off);
    if (lane == 0) out[(size_t)2176 * 2176] = sum * (1.0f / 128.0f);
}

extern "C" void kernel_launch(void* const* d_in, const int* in_sizes, int n_in,
                              void* d_out, int out_size, void* d_ws, size_t ws_size,
                              hipStream_t stream)
{
    const float* seg = (const float*)d_in[0];   // [128][512]
    const float* vid = (const float*)d_in[1];   // [2048][512]
    const float* W1  = (const float*)d_in[2];   // [256][1024]
    const float* b1  = (const float*)d_in[3];   // [256]
    const float* W2  = (const float*)d_in[4];   // [256]
    const float* b2  = (const float*)d_in[5];   // [1]
    float* out = (float*)d_out;
    float* ws  = (float*)d_ws;

    float* A2      = ws;             // 128*256
    float* B2      = ws + 32768;     // 2048*256
    float* logitsT = ws + 557056;    // 2048*128, [s][n]
    float* lsPK    = ws + 819200;    // 2048*128 packed [s/2][n][2]

    k1z_gemm<<<dim3(4760), dim3(256), 0, stream>>>(seg, vid, W1, b1, A2, B2, (float4*)out);
    k2_logits<<<dim3(2, 32), dim3(256), 0, stream>>>(A2, B2, W2, b2, logitsT, lsPK);
    k3_dp<<<dim3(1), dim3(64), 0, stream>>>(lsPK, logitsT, out);
}

// Round 7
// 192.387 us; speedup vs baseline: 1.2331x; 1.0067x over previous
//
#include <hip/hip_runtime.h>
#include <math.h>

#define NEGC (-1000.0f)

typedef float f32x4 __attribute__((ext_vector_type(4)));

// ---------- K1Z: blocks [0,136): GEMM  A2 = seg @ W1[:, :512]^T + b1 (128x256),
//                                       B2 = vid @ W1[:, 512:]^T     (2048x256)
//             blocks [136,4760): zero the adj matrix (2176*2176 floats) ----------
__global__ __launch_bounds__(256) void k1z_gemm(
    const float* __restrict__ seg, const float* __restrict__ vid,
    const float* __restrict__ W1, const float* __restrict__ b1,
    float* __restrict__ A2, float* __restrict__ B2, float4* __restrict__ out4)
{
    if (blockIdx.x >= 136) {
        const int i = (blockIdx.x - 136) * 256 + threadIdx.x;
        if (i < 1183744) out4[i] = make_float4(0.f, 0.f, 0.f, 0.f);
        return;
    }
    __shared__ float Xs[32][64];   // [kk][row]
    __shared__ float Ws[32][64];   // [kk][col]
    const int tid = threadIdx.x;
    const int tx = tid & 15, ty = tid >> 4;
    const int lr = tid >> 2;
    const int lk = (tid & 3) * 8;
    const int colBase = (blockIdx.x & 3) * 64;
    const int rowBase = (blockIdx.x >> 2) * 64;
    const bool isSeg = (rowBase < 128);
    const float* __restrict__ X = isSeg ? seg : vid;
    const int xRow = isSeg ? rowBase : (rowBase - 128);
    const int wOff = isSeg ? 0 : 512;

    float acc[4][4] = {};

    for (int k0 = 0; k0 < 512; k0 += 32) {
        const float* xp = X + (size_t)(xRow + lr) * 512 + (k0 + lk);
        const float4 xa = *(const float4*)xp;
        const float4 xb = *(const float4*)(xp + 4);
        const float* wp = W1 + (size_t)(colBase + lr) * 1024 + (wOff + k0 + lk);
        const float4 wa = *(const float4*)wp;
        const float4 wb = *(const float4*)(wp + 4);
        __syncthreads();
        Xs[lk + 0][lr] = xa.x; Xs[lk + 1][lr] = xa.y;
        Xs[lk + 2][lr] = xa.z; Xs[lk + 3][lr] = xa.w;
        Xs[lk + 4][lr] = xb.x; Xs[lk + 5][lr] = xb.y;
        Xs[lk + 6][lr] = xb.z; Xs[lk + 7][lr] = xb.w;
        Ws[lk + 0][lr] = wa.x; Ws[lk + 1][lr] = wa.y;
        Ws[lk + 2][lr] = wa.z; Ws[lk + 3][lr] = wa.w;
        Ws[lk + 4][lr] = wb.x; Ws[lk + 5][lr] = wb.y;
        Ws[lk + 6][lr] = wb.z; Ws[lk + 7][lr] = wb.w;
        __syncthreads();
        #pragma unroll
        for (int kk = 0; kk < 32; ++kk) {
            const float4 a4 = *(const float4*)&Xs[kk][4 * ty];
            const float4 b4 = *(const float4*)&Ws[kk][4 * tx];
            const float* a = (const float*)&a4;
            const float* b = (const float*)&b4;
            #pragma unroll
            for (int i = 0; i < 4; ++i)
                #pragma unroll
                for (int j = 0; j < 4; ++j)
                    acc[i][j] = fmaf(a[i], b[j], acc[i][j]);
        }
    }

    float* __restrict__ outp = (isSeg ? A2 : B2) + (size_t)xRow * 256;
    const int c = colBase + 4 * tx;
    #pragma unroll
    for (int i = 0; i < 4; ++i) {
        float4 v = make_float4(acc[i][0], acc[i][1], acc[i][2], acc[i][3]);
        if (isSeg) {
            v.x += b1[c + 0]; v.y += b1[c + 1]; v.z += b1[c + 2]; v.w += b1[c + 3];
        }
        *(float4*)(outp + (size_t)(4 * ty + i) * 256 + c) = v;
    }
}

// ---------- K2: logitsT[s][n] (for final gather) and lsPK packed [s/2][n][2]:
//   lsPK[s2*256 + 2n + (s&1)] = log_sigmoid(logits[n][s]) ----------
__global__ __launch_bounds__(256) void k2_logits(
    const float* __restrict__ A2, const float* __restrict__ B2,
    const float* __restrict__ W2, const float* __restrict__ b2p,
    float* __restrict__ logitsT, float* __restrict__ lsPK)
{
    __shared__ float As[32][64];   // [kk][n]
    __shared__ float Bs[32][64];   // [kk][s]
    __shared__ float w2s[256];
    const int tid = threadIdx.x;
    const int tx = tid & 15, ty = tid >> 4;
    const int lr = tid >> 2;
    const int lk = (tid & 3) * 8;
    const int nBase = blockIdx.x * 64;
    const int sBase = blockIdx.y * 64;
    w2s[tid] = W2[tid];
    const float b2v = b2p[0];

    float acc[4][4] = {};   // [i:n][j:s]

    for (int k0 = 0; k0 < 256; k0 += 32) {
        const float* ap = A2 + (size_t)(nBase + lr) * 256 + (k0 + lk);
        const float4 aa = *(const float4*)ap;
        const float4 ab = *(const float4*)(ap + 4);
        const float* bp = B2 + (size_t)(sBase + lr) * 256 + (k0 + lk);
        const float4 ba = *(const float4*)bp;
        const float4 bb = *(const float4*)(bp + 4);
        __syncthreads();
        As[lk + 0][lr] = aa.x; As[lk + 1][lr] = aa.y;
        As[lk + 2][lr] = aa.z; As[lk + 3][lr] = aa.w;
        As[lk + 4][lr] = ab.x; As[lk + 5][lr] = ab.y;
        As[lk + 6][lr] = ab.z; As[lk + 7][lr] = ab.w;
        Bs[lk + 0][lr] = ba.x; Bs[lk + 1][lr] = ba.y;
        Bs[lk + 2][lr] = ba.z; Bs[lk + 3][lr] = ba.w;
        Bs[lk + 4][lr] = bb.x; Bs[lk + 5][lr] = bb.y;
        Bs[lk + 6][lr] = bb.z; Bs[lk + 7][lr] = bb.w;
        __syncthreads();
        #pragma unroll
        for (int kk = 0; kk < 32; ++kk) {
            const float w = w2s[k0 + kk];
            const float4 a4 = *(const float4*)&As[kk][4 * ty];
            const float4 b4 = *(const float4*)&Bs[kk][4 * tx];
            const float* a = (const float*)&a4;
            const float* b = (const float*)&b4;
            #pragma unroll
            for (int i = 0; i < 4; ++i)
                #pragma unroll
                for (int j = 0; j < 4; ++j)
                    acc[i][j] = fmaf(fmaxf(a[i] + b[j], 0.0f), w, acc[i][j]);
        }
    }

    const int nb = nBase + 4 * ty;
    const int s0 = sBase + 4 * tx;          // even
    float lsv[4][4];                        // [j:s-offset][i:n-offset]
    #pragma unroll
    for (int j = 0; j < 4; ++j) {
        const int s = s0 + j;
        float4 lg;
        float* lgp = (float*)&lg;
        #pragma unroll
        for (int i = 0; i < 4; ++i) {
            const float x = acc[i][j] + b2v;
            lgp[i] = x;
            lsv[j][i] = fminf(x, 0.0f) - log1pf(expf(-fabsf(x)));
        }
        *(float4*)&logitsT[(size_t)s * 128 + nb] = lg;
    }
    #pragma unroll
    for (int m = 0; m < 2; ++m) {           // two s-pairs
        const size_t base = (size_t)(s0 / 2 + m) * 256 + 2 * nb;
        #pragma unroll
        for (int q = 0; q < 2; ++q) {       // two n-pairs
            float4 v = make_float4(lsv[2 * m][2 * q],     lsv[2 * m + 1][2 * q],
                                   lsv[2 * m][2 * q + 1], lsv[2 * m + 1][2 * q + 1]);
            *(float4*)&lsPK[base + 4 * q] = v;
        }
    }
}

// ---------- K3: sequential DP over s (one wave, 2 rows/lane), walk, outputs.
// ALL global loads in inline asm with counted vmcnt: 32 dwordx4 in flight,
// s_waitcnt vmcnt(28) per 8-step sub-group. Compiler cannot compress the pipe. ----------
__global__ __launch_bounds__(64, 1) void k3_dp(
    const float* __restrict__ lsPK, const float* __restrict__ logitsT,
    float* __restrict__ out)
{
    __shared__ unsigned takeW[128 * 65];   // [n][wordIdx], 65-pad
    __shared__ int alignSh[128];
    const int lane = threadIdx.x;
    const int n0 = 2 * lane, n1 = n0 + 1;

    float p0 = NEGC, p1 = NEGC;
    unsigned u0 = 2047u - (unsigned)n0;   // s - n0 (head phase)
    unsigned u1 = u0 - 1u;                // s - n1
    unsigned w0 = 0u, w1 = 0u;

    auto core = [&](float lx, float ly, float nx) {
        float c0, c1;
        unsigned long long cc;
        asm volatile(
            "v_add_f32 %[c0], %[lx], %[p1]\n\t"
            "v_add_f32 %[c1], %[ly], %[nx]\n\t"
            "v_cmp_ge_f32 vcc, %[c0], %[p0]\n\t"
            "v_cmp_ge_f32 %[cc], %[c1], %[p1]\n\t"
            "v_addc_co_u32 %[w0], vcc, %[w0], %[w0], vcc\n\t"
            "v_addc_co_u32 %[w1], %[cc], %[w1], %[w1], %[cc]\n\t"
            "v_max_f32 %[p0], %[c0], %[p0]\n\t"
            "v_max_f32 %[p1], %[c1], %[p1]\n\t"
            : [p0]"+v"(p0), [p1]"+v"(p1), [w0]"+v"(w0), [w1]"+v"(w1),
              [c0]"=&v"(c0), [c1]"=&v"(c1), [cc]"=&s"(cc)
            : [lx]"v"(lx), [ly]"v"(ly), [nx]"v"(nx)
            : "vcc");
    };

    auto stepF = [&](float lx, float ly) { // in-band: no range masking
        float nxt1 = __int_as_float(__builtin_amdgcn_update_dpp(
            0, __float_as_int(p0), 0x130 /*WAVE_SHL1*/, 0xf, 0xf, true));
        core(lx, ly, nxt1);
    };
    auto stepM = [&](float lx, float ly) { // masked (head/tail)
        float nxt1 = __int_as_float(__builtin_amdgcn_update_dpp(
            0, __float_as_int(p0), 0x130, 0xf, 0xf, true));
        core(lx, ly, nxt1);
        p0 = (u0 <= 1920u) ? p0 : NEGC;   // 0 <= s-n <= 1920 (wrap covers s<n)
        p1 = (u1 <= 1920u) ? p1 : NEGC;
        --u0; --u1;
    };

    // 8 buffers x 4 float4, asm-pinned. One running 32-bit voffset, SGPR base.
    unsigned voff = 1023u * 1024u + (unsigned)lane * 16u;
    f32x4 B00, B01, B02, B03, B10, B11, B12, B13, B20, B21, B22, B23,
          B30, B31, B32, B33, B40, B41, B42, B43, B50, B51, B52, B53,
          B60, B61, B62, B63, B70, B71, B72, B73;

#define GL(B) asm volatile( \
    "global_load_dwordx4 %0, %1, %2\n\t" \
    "v_add_u32 %1, 0xfffffc00, %1" \
    : "=&v"(B), "+v"(voff) : "s"(lsPK) : "memory");
#define WAITC(n) asm volatile("s_waitcnt vmcnt(" #n ")" ::: "memory");
#define GL4(Ba,Bb,Bc,Bd) GL(Ba) GL(Bb) GL(Bc) GL(Bd)
    // quad = {even.n0, odd.n0, even.n1, odd.n1}; descending s: odd first
#define CONS_F(Ba,Bb,Bc,Bd) { \
    stepF(Ba.y, Ba.w); stepF(Ba.x, Ba.z); stepF(Bb.y, Bb.w); stepF(Bb.x, Bb.z); \
    stepF(Bc.y, Bc.w); stepF(Bc.x, Bc.z); stepF(Bd.y, Bd.w); stepF(Bd.x, Bd.z); }
#define CONS_M(Ba,Bb,Bc,Bd) { \
    stepM(Ba.y, Ba.w); stepM(Ba.x, Ba.z); stepM(Bb.y, Bb.w); stepM(Bb.x, Bb.z); \
    stepM(Bc.y, Bc.w); stepM(Bc.x, Bc.z); stepM(Bd.y, Bd.w); stepM(Bd.x, Bd.z); }
#define SUBF(Ba,Bb,Bc,Bd) { WAITC(28) CONS_F(Ba,Bb,Bc,Bd) GL4(Ba,Bb,Bc,Bd) }
#define SUBM(Ba,Bb,Bc,Bd) { WAITC(28) CONS_M(Ba,Bb,Bc,Bd) GL4(Ba,Bb,Bc,Bd) }
#define FLUSH { takeW[n0 * 65 + wIdx] = w0; takeW[n1 * 65 + wIdx] = w1; \
                w0 = 0u; w1 = 0u; --wIdx; }
#define ITER(SUB) \
    SUB(B00,B01,B02,B03) SUB(B10,B11,B12,B13) \
    SUB(B20,B21,B22,B23) SUB(B30,B31,B32,B33) FLUSH \
    SUB(B40,B41,B42,B43) SUB(B50,B51,B52,B53) \
    SUB(B60,B61,B62,B63) SUB(B70,B71,B72,B73) FLUSH

    // prologue: 32 loads in flight (sub-groups 0..7)
    GL4(B00,B01,B02,B03) GL4(B10,B11,B12,B13) GL4(B20,B21,B22,B23) GL4(B30,B31,B32,B33)
    GL4(B40,B41,B42,B43) GL4(B50,B51,B52,B53) GL4(B60,B61,B62,B63) GL4(B70,B71,B72,B73)

    int wIdx = 63;
    // head: sub-groups 0..15 (s 2047..1920) — masked
    for (int it = 0; it < 2; ++it) { ITER(SUBM) }
    // mid: sub-groups 16..239 (s 1919..128) — in-band
    for (int it = 0; it < 28; ++it) { ITER(SUBF) }
    // tail part 1: sub-groups 240..247 (s 127..64) — masked; reset u = s - n at s=127
    u0 = (unsigned)(127 - n0);
    u1 = u0 - 1u;
    ITER(SUBM)
    // epilogue: sub-groups 248..255 (s 63..0) — masked, drain vmcnt 28 -> 0
    WAITC(24) CONS_M(B00,B01,B02,B03)
    WAITC(20) CONS_M(B10,B11,B12,B13)
    WAITC(16) CONS_M(B20,B21,B22,B23)
    WAITC(12) CONS_M(B30,B31,B32,B33) FLUSH
    WAITC(8)  CONS_M(B40,B41,B42,B43)
    WAITC(4)  CONS_M(B50,B51,B52,B53)
    WAITC(2)  CONS_M(B60,B61,B62,B63)
    WAITC(0)  CONS_M(B70,B71,B72,B73) FLUSH
#undef ITER
#undef FLUSH
#undef SUBM
#undef SUBF
#undef CONS_M
#undef CONS_F
#undef GL4
#undef WAITC
#undef GL

    alignSh[n0] = 0;
    alignSh[n1] = 0;
    __syncthreads();

    // wave-parallel walk: lane holds word 'lane' of row n; ballot -> first set bit
    int pos = 0;
    for (int n = 0; n < 128; ++n) {
        unsigned w = takeW[n * 65 + lane];
        const int wi0 = pos >> 5;
        if (lane < wi0) w = 0u;
        else if (lane == wi0) w &= (0xFFFFFFFFu << (pos & 31));
        const unsigned long long m = __ballot(w != 0u);
        if (m == 0ull) break;             // uniform
        const int fl = __builtin_ctzll(m);
        const unsigned fw = (unsigned)__builtin_amdgcn_readlane((int)w, fl);
        const int s = fl * 32 + __builtin_ctz(fw);
        if (lane == 0) alignSh[n] = s;
        pos = s + 1;
    }
    __syncthreads();

    const int a0 = alignSh[n0];
    const int a1 = alignSh[n1];
    out[(size_t)(2048 + n0) * 2176 + a0] = 1.0f;
    out[(size_t)(2048 + n1) * 2176 + a1] = 1.0f;
    float sum = logitsT[(size_t)a0 * 128 + n0] + logitsT[(size_t)a1 * 128 + n1];
    #pragma unroll
    for (int off = 32; off >= 1; off >>= 1) sum += __shfl_down(sum, off);
    if (lane == 0) out[(size_t)2176 * 2176] = sum * (1.0f / 128.0f);
}

extern "C" void kernel_launch(void* const* d_in, const int* in_sizes, int n_in,
                              void* d_out, int out_size, void* d_ws, size_t ws_size,
                              hipStream_t stream)
{
    const float* seg = (const float*)d_in[0];   // [128][512]
    const float* vid = (const float*)d_in[1];   // [2048][512]
    const float* W1  = (const float*)d_in[2];   // [256][1024]
    const float* b1  = (const float*)d_in[3];   // [256]
    const float* W2  = (const float*)d_in[4];   // [256]
    const float* b2  = (const float*)d_in[5];   // [1]
    float* out = (float*)d_out;
    float* ws  = (float*)d_ws;

    float* A2      = ws;             // 128*256
    float* B2      = ws + 32768;     // 2048*256
    float* logitsT = ws + 557056;    // 2048*128, [s][n]
    float* lsPK    = ws + 819200;    // 2048*128 packed [s/2][n][2]

    k1z_gemm<<<dim3(4760), dim3(256), 0, stream>>>(seg, vid, W1, b1, A2, B2, (float4*)out);
    k2_logits<<<dim3(2, 32), dim3(256), 0, stream>>>(A2, B2, W2, b2, logitsT, lsPK);
    k3_dp<<<dim3(1), dim3(64), 0, stream>>>(lsPK, logitsT, out);
}